// Round 1
// baseline (659.351 us; speedup 1.0000x reference)
//
#include <hip/hip_runtime.h>

// NeighborSample: x[8,64,64,192] f32 -> out[8*64*64, 5, 5, 192] f32
// out[((p*5+i)*5+j)*192 + k] = x[b, y+i-2, x+j-2, k] (zero-padded)
// Pure streaming gather: 600 MiB written, 24 MiB input (L2/L3 resident).
// One thread per output float4 (C=192 -> 48 float4 per channel row).

constexpr int B = 8;
constexpr int H = 64;
constexpr int W = 64;
constexpr int C = 192;
constexpr int C4 = C / 4;          // 48 float4 per row
constexpr int K = 5;
constexpr int PAD = K / 2;

constexpr unsigned TOTAL_F4 = (unsigned)B * H * W * K * K * C4;  // 39,321,600
constexpr int BLOCK = 256;

__global__ __launch_bounds__(BLOCK) void neighbor_sample_kernel(
    const float4* __restrict__ in, float4* __restrict__ out) {
  unsigned gid = blockIdx.x * BLOCK + threadIdx.x;  // grid sized exactly

  // Decompose: gid = ((p * 25 + pos) * 48) + k4
  unsigned k4   = gid % C4;
  unsigned rest = gid / C4;        // p * 25 + pos
  unsigned pos  = rest % (K * K);
  unsigned p    = rest / (K * K);  // pixel index, < 32768

  int i = (int)(pos / K);          // 0..4
  int j = (int)(pos % K);

  int xx = (int)(p & (W - 1));
  int yy = (int)((p >> 6) & (H - 1));
  int b  = (int)(p >> 12);

  int sy = yy + i - PAD;
  int sx = xx + j - PAD;

  float4 v = make_float4(0.f, 0.f, 0.f, 0.f);
  if ((unsigned)sy < (unsigned)H && (unsigned)sx < (unsigned)W) {
    unsigned src = (((unsigned)(b * H + sy) * W) + (unsigned)sx) * C4 + k4;
    v = in[src];
  }
  out[gid] = v;
}

extern "C" void kernel_launch(void* const* d_in, const int* in_sizes, int n_in,
                              void* d_out, int out_size, void* d_ws, size_t ws_size,
                              hipStream_t stream) {
  const float4* in = (const float4*)d_in[0];
  float4* out = (float4*)d_out;
  unsigned grid = TOTAL_F4 / BLOCK;  // 153,600 blocks, exact
  neighbor_sample_kernel<<<grid, BLOCK, 0, stream>>>(in, out);
}